// Round 11
// baseline (2156.634 us; speedup 1.0000x reference)
//
#include <hip/hip_runtime.h>
#include <cstdint>
#include <cstddef>

// Problem dims (fixed). Inputs fp32, output fp32.
#define B_DIM 1024
#define T_DIM 32
#define V_DIM 1024
#define E_DIM 512
#define H_DIM 1024
#define O_DIM 1024

typedef unsigned short u16;
typedef __attribute__((ext_vector_type(8))) __bf16 bf16x8;  // MFMA A/B frag
typedef __attribute__((ext_vector_type(4))) float f32x4;    // MFMA C/D frag

__device__ __forceinline__ float bf2f(u16 u) {
  union { unsigned int i; float f; } v; v.i = ((unsigned int)u) << 16; return v.f;
}
__device__ __forceinline__ u16 f2bf(float f) {
  union { float f; unsigned int i; } v; v.f = f;
  return (u16)((v.i + 0x7fffu + ((v.i >> 16) & 1u)) >> 16);  // RNE
}
// async global->LDS, 16B/lane; HW writes lds_base + lane*16 (wave-uniform base)
__device__ __forceinline__ void async_cp16(const void* g, void* l) {
  __builtin_amdgcn_global_load_lds(
      (const __attribute__((address_space(1))) void*)g,
      (__attribute__((address_space(3))) void*)l, 16, 0, 0);
}
// fast tanh via hw exp+rcp: exact at +-inf, |err| ~1e-6 (<< bf16 ulp)
__device__ __forceinline__ float fast_tanh(float v) {
  return 1.f - 2.f / (__expf(2.f * v) + 1.f);
}

// ---------------------------------------------------------------------------
// Fused prep (memory work only):
//  blocks [0,2048):    convert msg/W_hh/W_out fp32->bf16 (grid-stride)
//  blocks [2048,2176): W_ih -> A3 = [hi | lo | hi]  (1024 x 1536 bf16)
//  blocks [2176,2304): W_emb -> B3 = [hi | hi | lo] transposed (1024 x 1536)
//  blocks [2304,2308): bcomb
// ---------------------------------------------------------------------------
__global__ __launch_bounds__(256) void prep_all(
    const float* __restrict__ Whh, const float* __restrict__ Wout,
    const float* __restrict__ msg, const float* __restrict__ Wih,
    const float* __restrict__ Wemb, const float* __restrict__ bemb,
    const float* __restrict__ bih, u16* __restrict__ dWhh,
    u16* __restrict__ dWout, u16* __restrict__ dmsg,
    u16* __restrict__ A3, u16* __restrict__ B3, float* __restrict__ bc) {
  __shared__ __align__(16) float T[64][65];
  const int bid = blockIdx.x, tid = threadIdx.x;
  if (bid < 2048) {  // ---- convert (pure BW) ----
    const int QW = 262144;            // 1M elems / 4
    const int QM = 8388608;           // 32M elems / 4
    const int total = dmsg ? (2 * QW + QM) : (2 * QW);
    int i = bid * 256 + tid;
    const int stride = 2048 * 256;
    for (; i < total; i += stride) {
      const float4* src; ushort4* dst; int j;
      if (i < QW)          { src = (const float4*)Whh;  dst = (ushort4*)dWhh;  j = i; }
      else if (i < 2 * QW) { src = (const float4*)Wout; dst = (ushort4*)dWout; j = i - QW; }
      else                 { src = (const float4*)msg;  dst = (ushort4*)dmsg;  j = i - 2 * QW; }
      float4 v = src[j];
      ushort4 o = {f2bf(v.x), f2bf(v.y), f2bf(v.z), f2bf(v.w)};
      dst[j] = o;
    }
  } else if (bid < 2176) {  // ---- W_ih -> A3 [hi|lo|hi] ----
    const int b8 = bid - 2048;  // 0..127, 8 rows each
    const float4* W4 = (const float4*)Wih;
#pragma unroll
    for (int it = 0; it < 4; ++it) {
      int i = it * 256 + tid;            // 0..1023
      int r = b8 * 8 + (i >> 7), c4 = i & 127;
      float4 v = W4[(size_t)r * 128 + c4];
      ushort4 hi = {f2bf(v.x), f2bf(v.y), f2bf(v.z), f2bf(v.w)};
      ushort4 lo = {f2bf(v.x - bf2f(hi.x)), f2bf(v.y - bf2f(hi.y)),
                    f2bf(v.z - bf2f(hi.z)), f2bf(v.w - bf2f(hi.w))};
      u16* base = A3 + (size_t)r * 1536 + c4 * 4;
      *(ushort4*)(base)        = hi;
      *(ushort4*)(base + 512)  = lo;
      *(ushort4*)(base + 1024) = hi;
    }
  } else if (bid < 2304) {  // ---- W_emb transpose -> B3 [hi|hi|lo] ----
    const int b = bid - 2176;                    // 0..127
    const int e0 = (b >> 4) * 64, v0 = (b & 15) * 64;
#pragma unroll
    for (int ps = 0; ps < 16; ++ps) {
      int r = ps * 4 + (tid >> 6), c = tid & 63;
      T[r][c] = Wemb[(size_t)(e0 + r) * V_DIM + v0 + c];
    }
    __syncthreads();
#pragma unroll
    for (int ps = 0; ps < 16; ++ps) {
      int vr = ps * 4 + (tid >> 6), ec = tid & 63;
      float wv = T[ec][vr];                      // transposed read, stride 65
      u16 hi = f2bf(wv);
      u16 lo = f2bf(wv - bf2f(hi));
      u16* base = B3 + (size_t)(v0 + vr) * 1536 + e0 + ec;
      base[0]    = hi;
      base[512]  = hi;
      base[1024] = lo;
    }
  } else {  // ---- bcomb ----
    int h = (bid - 2304) * 256 + tid;
    float s = 0.f;
    for (int e = 0; e < E_DIM; ++e) s += Wih[(size_t)h * E_DIM + e] * bemb[e];
    bc[h] = s + bih[h];
  }
}

// ---------------------------------------------------------------------------
// W_comb via MFMA: Wc[h][v] = A3[h,:].B3[v,:] (K=1536 = hihi+lohi+hilo).
// 64x64 tiles, grid 256, depth-3 counted vmcnt, XOR-swizzled (verified R10).
// ---------------------------------------------------------------------------
__global__ __launch_bounds__(256) void wcomb_mfma(
    const u16* __restrict__ A3, const u16* __restrict__ B3,
    u16* __restrict__ Wc) {
  __shared__ __align__(16) u16 lds[24576];  // 3 x 8KB
  const int tid = threadIdx.x, lane = tid & 63, w = tid >> 6;
  const int lrow = lane >> 4, lcol = lane & 15;
  const int l7 = lane & 7, r8 = lane >> 3;
  const int p = blockIdx.x;
  const int xcd = p & 7, q = p >> 3;
  const int mt = xcd * 2 + (q >> 4), nt = q & 15;
  const int m0 = mt * 64, n0 = nt * 64;  // m0 = h band, n0 = v band
  const int mq = (w & 1) * 32, nq = (w >> 1) * 32;
  const int half = w >> 1, wv = w & 1;

  auto stage = [&](int kk, int d) {
    const u16* src = half ? B3 : A3;
    const int rbase = half ? n0 : m0;
#pragma unroll
    for (int i = 0; i < 4; ++i) {
      int row = wv * 32 + i * 8 + r8;
      async_cp16(src + (size_t)(rbase + row) * 1536 + kk * 64 + ((l7 ^ r8) << 3),
                 lds + d * 8192 + half * 4096 + (wv * 32 + i * 8) * 64);
    }
  };
  f32x4 acc[2][2] = {};
  auto kchunk = [&](int d) {
    const u16* base = lds + d * 8192;
#pragma unroll
    for (int ks = 0; ks < 2; ++ks) {
      const int ce = ks * 32 + lrow * 8;
      int rA0 = mq + lcol, rA1 = mq + 16 + lcol;
      int rB0 = nq + lcol, rB1 = nq + 16 + lcol;
      bf16x8 a0 = *(const bf16x8*)(lds + d * 8192 + rA0 * 64 + (ce ^ ((rA0 & 7) << 3)));
      bf16x8 a1 = *(const bf16x8*)(lds + d * 8192 + rA1 * 64 + (ce ^ ((rA1 & 7) << 3)));
      bf16x8 b0 = *(const bf16x8*)(base + 4096 + rB0 * 64 + (ce ^ ((rB0 & 7) << 3)));
      bf16x8 b1 = *(const bf16x8*)(base + 4096 + rB1 * 64 + (ce ^ ((rB1 & 7) << 3)));
      acc[0][0] = __builtin_amdgcn_mfma_f32_16x16x32_bf16(a0, b0, acc[0][0], 0, 0, 0);
      acc[0][1] = __builtin_amdgcn_mfma_f32_16x16x32_bf16(a0, b1, acc[0][1], 0, 0, 0);
      acc[1][0] = __builtin_amdgcn_mfma_f32_16x16x32_bf16(a1, b0, acc[1][0], 0, 0, 0);
      acc[1][1] = __builtin_amdgcn_mfma_f32_16x16x32_bf16(a1, b1, acc[1][1], 0, 0, 0);
    }
  };
  stage(0, 0); stage(1, 1); stage(2, 2);
#pragma unroll
  for (int kk = 0; kk < 24; ++kk) {
    if (kk <= 21)      asm volatile("s_waitcnt vmcnt(8)" ::: "memory");
    else if (kk == 22) asm volatile("s_waitcnt vmcnt(4)" ::: "memory");
    else               asm volatile("s_waitcnt vmcnt(0)" ::: "memory");
    __builtin_amdgcn_s_barrier();
    kchunk(kk % 3);
    __builtin_amdgcn_s_barrier();
    if (kk <= 20) stage(kk + 3, kk % 3);
  }
#pragma unroll
  for (int i = 0; i < 2; ++i)
#pragma unroll
    for (int rr = 0; rr < 4; ++rr) {
      int hrow = m0 + mq + i * 16 + lrow * 4 + rr;
#pragma unroll
      for (int j = 0; j < 2; ++j)
        Wc[(size_t)hrow * V_DIM + n0 + nq + j * 16 + lcol] = f2bf(acc[i][j][rr]);
    }
}

// ---------------------------------------------------------------------------
// xproj GEMM (R9/R10-verified): 128x128 tiles, XCD band remap, XOR-swizzled,
// depth-2 double-buffer (2 blocks/CU), t=0 fold (h0 -> xp slot 0).
// ---------------------------------------------------------------------------
__global__ __launch_bounds__(256) void gemm_xp(
    const u16* __restrict__ A, const u16* __restrict__ Bm,
    const float* __restrict__ bias, const float* __restrict__ bhh,
    u16* __restrict__ outp) {
  __shared__ __align__(16) u16 lds[32768];  // 2 x 16KB(A)+16KB(B)
  const int tid = threadIdx.x, lane = tid & 63, w = tid >> 6;
  const int lrow = lane >> 4, lcol = lane & 15;
  const int l7 = lane & 7, r8 = lane >> 3;
  const int p = blockIdx.x;
  const int xk = p & 7, q = p >> 3;
  const int mt = xk * 32 + (q >> 3), nt = q & 7;
  const int m0 = mt * 128, n0 = nt * 128;
  const int mq = (w & 1) * 64, nq = (w >> 1) * 64;
  const int half = w >> 1, wv = w & 1;  // waves 0,1 stage A; 2,3 stage B

  auto stage = [&](int kk, int d) {
    const u16* src = half ? Bm : A;
    const int rbase = half ? n0 : m0;
#pragma unroll
    for (int i = 0; i < 8; ++i) {
      int row = wv * 64 + i * 8 + r8;
      async_cp16(src + (size_t)(rbase + row) * H_DIM + kk * 64 + ((l7 ^ r8) << 3),
                 lds + d * 16384 + half * 8192 + (wv * 64 + i * 8) * 64);
    }
  };

  f32x4 acc[4][4] = {};
  auto kchunk = [&](int d) {
    const u16* base = lds + d * 16384;
#pragma unroll
    for (int ks = 0; ks < 2; ++ks) {
      const int ce = ks * 32 + lrow * 8;
      bf16x8 a[4], b[4];
#pragma unroll
      for (int i = 0; i < 4; ++i) {
        int row = mq + i * 16 + lcol;
        a[i] = *(const bf16x8*)(base + row * 64 + (ce ^ ((row & 7) << 3)));
      }
#pragma unroll
      for (int i = 0; i < 4; ++i) {
        int row = nq + i * 16 + lcol;
        b[i] = *(const bf16x8*)(base + 8192 + row * 64 + (ce ^ ((row & 7) << 3)));
      }
#pragma unroll
      for (int i = 0; i < 4; ++i)
#pragma unroll
        for (int j = 0; j < 4; ++j)
          acc[i][j] = __builtin_amdgcn_mfma_f32_16x16x32_bf16(a[i], b[j], acc[i][j], 0, 0, 0);
    }
  };

  stage(0, 0); stage(1, 1);
#pragma unroll
  for (int kk = 0; kk < 16; ++kk) {
    if (kk <= 14) asm volatile("s_waitcnt vmcnt(8)" ::: "memory");
    else          asm volatile("s_waitcnt vmcnt(0)" ::: "memory");
    __builtin_amdgcn_s_barrier();   // chunk kk LDS-visible to all waves
    kchunk(kk & 1);
    __builtin_amdgcn_s_barrier();   // all reads of buf kk&1 done
    if (kk <= 13) stage(kk + 2, kk & 1);
  }

  float bv[4], bh[4];
#pragma unroll
  for (int j = 0; j < 4; ++j) {
    bv[j] = bias[n0 + nq + j * 16 + lcol];
    bh[j] = bhh[n0 + nq + j * 16 + lcol];
  }
#pragma unroll
  for (int i = 0; i < 4; ++i)
#pragma unroll
    for (int rr = 0; rr < 4; ++rr) {
      int rg = m0 + mq + i * 16 + lrow * 4 + rr;  // flat (b*T + t)
      int bI = rg >> 5, tI = rg & 31;
      u16* dst = outp + ((size_t)tI * B_DIM + bI) * H_DIM + n0 + nq;
      if (tI == 0) {  // t=0 fold: h0 = tanh(x0 + bhh), full fp32 precision
#pragma unroll
        for (int j = 0; j < 4; ++j)
          dst[j * 16 + lcol] = f2bf(fast_tanh(acc[i][j][rr] + bv[j] + bh[j]));
      } else {
#pragma unroll
        for (int j = 0; j < 4; ++j)
          dst[j * 16 + lcol] = f2bf(acc[i][j][rr] + bv[j]);
      }
    }
}

// ---------------------------------------------------------------------------
// ONE-LAUNCH RNN: the recurrence is ROW-LOCAL (h[t][m,:] depends only on
// h[t-1][m,:]), so a block owning a 16-row batch band and ALL 1024 output
// columns needs NO cross-block sync. 64 blocks x 512 threads (8 waves, each
// owning a 128-col slice). h (16x1024 bf16 = 32 KB) stays in LDS (XOR-swz)
// across all steps; W streams global->VGPR (L2-hot, 16rows x 64B per frag,
// no LDS staging, no K-loop barriers); manual 2x double-buffer, static idx.
// t=1..31 vs Whh (+x_t, tanh, write h to LDS); t=32 streams Wout -> fp32 out.
// ---------------------------------------------------------------------------
__global__ __launch_bounds__(512, 1) void rnn_all(
    const u16* __restrict__ Whh_b, const u16* __restrict__ Wout_b,
    const u16* __restrict__ xp, const float* __restrict__ bhh,
    const float* __restrict__ bout, float* __restrict__ outp) {
  __shared__ __align__(16) u16 hl[16 * 1024];  // 32 KB, col-swizzled per row
  const int tid = threadIdx.x, lane = tid & 63, w = tid >> 6;  // 8 waves
  const int lrow = lane >> 4, lcol = lane & 15;
  const int m0 = blockIdx.x * 16;   // batch-row band
  const int nb = w * 128;           // wave's output-col base

  // stage h0 = xp[0] rows m0..m0+15 into hl, swizzled via pre-swz source col
  {
    const u16* src = xp + (size_t)m0 * H_DIM;
#pragma unroll
    for (int j = 0; j < 4; ++j) {
      int row = w * 2 + (j >> 1);            // wave-uniform
      int chalf = (j & 1) * 512;             // elems
      int csrc = (chalf + lane * 8) ^ ((row & 7) << 3);
      async_cp16(src + (size_t)row * H_DIM + csrc, hl + row * 1024 + chalf);
    }
    asm volatile("s_waitcnt vmcnt(0)" ::: "memory");
    __syncthreads();
  }
  float bhv[8], bov[8];
#pragma unroll
  for (int nt = 0; nt < 8; ++nt) {
    bhv[nt] = bhh[nb + nt * 16 + lcol];
    bov[nt] = bout[nb + nt * 16 + lcol];
  }

  for (int t = 1; t <= 32; ++t) {
    const bool is_out = (t == 32);
    const u16* W = is_out ? Wout_b : Whh_b;
    // x_t epilogue values: issue early, consumed after K-loop
    u16 xv[8][4];
    if (!is_out) {
      const u16* xr = xp + (size_t)t * (B_DIM * H_DIM);
#pragma unroll
      for (int nt = 0; nt < 8; ++nt)
#pragma unroll
        for (int rr = 0; rr < 4; ++rr)
          xv[nt][rr] = xr[(size_t)(m0 + lrow * 4 + rr) * H_DIM + nb + nt * 16 + lcol];
    }
    f32x4 acc[8];
#pragma unroll
    for (int nt = 0; nt < 8; ++nt) acc[nt] = (f32x4){0.f, 0.f, 0.f, 0.f};

    bf16x8 bA[8], bB[8], aA, aB;
    auto loadB = [&](bf16x8* dst, int kk) {
#pragma unroll
      for (int nt = 0; nt < 8; ++nt)
        dst[nt] = *(const bf16x8*)(W + (size_t)(nb + nt * 16 + lcol) * H_DIM +
                                   kk * 32 + lrow * 8);
    };
    auto loadA = [&](bf16x8& d, int kk) {
      int c = (kk * 32 + lrow * 8) ^ ((lcol & 7) << 3);  // A row = lcol
      d = *(const bf16x8*)(hl + lcol * 1024 + c);
    };
    loadA(aA, 0); loadB(bA, 0);
#pragma unroll
    for (int kp = 0; kp < 16; ++kp) {
      const int k0 = kp * 2;
      loadA(aB, k0 + 1); loadB(bB, k0 + 1);          // k0+1 <= 31, valid
#pragma unroll
      for (int nt = 0; nt < 8; ++nt)
        acc[nt] = __builtin_amdgcn_mfma_f32_16x16x32_bf16(aA, bA[nt], acc[nt], 0, 0, 0);
      const int kn = (k0 + 2 <= 31) ? k0 + 2 : 31;   // clamp; last value unused
      loadA(aA, kn); loadB(bA, kn);
#pragma unroll
      for (int nt = 0; nt < 8; ++nt)
        acc[nt] = __builtin_amdgcn_mfma_f32_16x16x32_bf16(aB, bB[nt], acc[nt], 0, 0, 0);
    }
    __syncthreads();  // all waves done READING hl
    if (!is_out) {
#pragma unroll
      for (int nt = 0; nt < 8; ++nt)
#pragma unroll
        for (int rr = 0; rr < 4; ++rr) {
          int row = lrow * 4 + rr;                   // C layout: row, col
          int col = nb + nt * 16 + lcol;
          float v = acc[nt][rr] + bhv[nt] + bf2f(xv[nt][rr]);
          hl[row * 1024 + (col ^ ((row & 7) << 3))] = f2bf(fast_tanh(v));
        }
      __syncthreads();  // h(t) ready for next step
    } else {
#pragma unroll
      for (int nt = 0; nt < 8; ++nt)
#pragma unroll
        for (int rr = 0; rr < 4; ++rr) {
          int row = lrow * 4 + rr;
          outp[(size_t)(m0 + row) * O_DIM + nb + nt * 16 + lcol] =
              acc[nt][rr] + bov[nt];
        }
    }
  }
}

// ---------------------------------------------------------------------------
// FALLBACK kernels for small workspace (R5/R7-verified, unchanged).
// ---------------------------------------------------------------------------
__global__ __launch_bounds__(256) void xproj_mfma(
    const float* __restrict__ msg, const u16* __restrict__ Wc,
    const float* __restrict__ bc, u16* __restrict__ xp) {
  __shared__ u16 As[128 * 64];
  __shared__ u16 Bs[128 * 64];
  const int tid = threadIdx.x, lane = tid & 63, w = tid >> 6;
  const int lrow = lane >> 4, lcol = lane & 15;
  const int p = blockIdx.y * gridDim.x + blockIdx.x;
  const int xk = p & 7, q = p >> 3;
  const int m0 = (xk * 32 + (q >> 3)) * 128;
  const int n0 = (q & 7) * 128;
  const int mq = (w & 1) * 64, nq = (w >> 1) * 64;
  f32x4 acc[4][4] = {};
  const int r8 = lane >> 3, l7 = lane & 7;
  const int ar = tid >> 1, ak = (tid & 1) * 32;

  auto stageB = [&](int kk) {
#pragma unroll
    for (int i = 0; i < 4; ++i) {
      int ch = w * 4 + i;
      async_cp16(Wc + (size_t)(n0 + ch * 8 + r8) * V_DIM + kk * 64 + ((l7 ^ r8) << 3),
                 Bs + ch * 512);
    }
  };
  float4 areg[8];
  auto loadA = [&](int kk) {
    const float4* src = (const float4*)(msg + (size_t)(m0 + ar) * V_DIM + kk * 64 + ak);
#pragma unroll
    for (int i = 0; i < 8; ++i) areg[i] = src[i];
  };
  auto writeA = [&]() {
    u16 tmp[32];
#pragma unroll
    for (int i = 0; i < 8; ++i) {
      tmp[i * 4 + 0] = f2bf(areg[i].x);
      tmp[i * 4 + 1] = f2bf(areg[i].y);
      tmp[i * 4 + 2] = f2bf(areg[i].z);
      tmp[i * 4 + 3] = f2bf(areg[i].w);
    }
#pragma unroll
    for (int i = 0; i < 4; ++i) {
      int c = (ak + i * 8) ^ ((ar & 7) << 3);
      *(uint4*)(As + (size_t)ar * 64 + c) = *(const uint4*)(tmp + i * 8);
    }
  };

  loadA(0);
  stageB(0);
  writeA();
  for (int kk = 0; kk < 16; ++kk) {
    __syncthreads();
    if (kk < 15) loadA(kk + 1);
#pragma unroll
    for (int ks = 0; ks < 2; ++ks) {
      const int kb = ks * 32 + lrow * 8;
      bf16x8 a[4], b[4];
#pragma unroll
      for (int i = 0; i < 4; ++i) {
        int row = mq + i * 16 + lcol;
        a[i] = *(const bf16x8*)(As + row * 64 + (kb ^ ((row & 7) << 3)));
      }
#pragma unroll
      for (int i = 0; i < 4; ++i) {
        int row = nq + i * 16 + lcol;
        b[i] = *(const bf16x8*)(Bs + row * 64 + (kb ^ ((row & 7) << 3)));
      }
#pragma unroll
      for (int i = 0; i < 4; ++i)
#pragma unroll
        for (int j = 0; j < 4; ++j)
          acc[i][j] = __builtin_amdgcn_mfma_f32_16x16x32_bf16(a[i], b[j], acc[i][j], 0, 0, 0);
    }
    __syncthreads();
    if (kk < 15) { stageB(kk + 1); writeA(); }
  }
  float bcv[4];
#pragma unroll
  for (int j = 0; j < 4; ++j) bcv[j] = bc[n0 + nq + j * 16 + lcol];
#pragma unroll
  for (int i = 0; i < 4; ++i)
#pragma unroll
    for (int rr = 0; rr < 4; ++rr) {
      int rg = m0 + mq + i * 16 + lrow * 4 + rr;
      int bI = rg >> 5, tI = rg & 31;
      u16* dst = xp + ((size_t)tI * B_DIM + bI) * H_DIM + n0 + nq;
#pragma unroll
      for (int j = 0; j < 4; ++j)
        dst[j * 16 + lcol] = f2bf(acc[i][j][rr] + bcv[j]);
    }
}

template <int MODE>
__global__ __launch_bounds__(256) void step64(
    const u16* __restrict__ A, const u16* __restrict__ Bm,
    const u16* __restrict__ x, const float* __restrict__ bias,
    void* __restrict__ outp) {
  constexpr int XOFF = 24576;  // elems
  constexpr int LDSE = (MODE == 1) ? 28672 : 24576;
  __shared__ __align__(16) u16 lds[LDSE];
  const int tid = threadIdx.x, lane = tid & 63, w = tid >> 6;
  const int lrow = lane >> 4, lcol = lane & 15;
  const int l7 = lane & 7, r8 = lane >> 3;
  const int p = blockIdx.x;
  const int xcd = p & 7, q = p >> 3;
  const int mt = xcd * 2 + (q >> 4), nt = q & 15;
  const int m0 = mt * 64, n0 = nt * 64;
  const int mq = (w & 1) * 32, nq = (w >> 1) * 32;
  const int half = w >> 1, wv = w & 1;

  auto stage = [&](int kk, int d) {
    const u16* src = half ? Bm : A;
    const int rbase = half ? n0 : m0;
#pragma unroll
    for (int i = 0; i < 4; ++i) {
      int row = wv * 32 + i * 8 + r8;
      async_cp16(src + (size_t)(rbase + row) * H_DIM + kk * 64 + ((l7 ^ r8) << 3),
                 lds + d * 8192 + half * 4096 + (wv * 32 + i * 8) * 64);
    }
  };
  auto stage_x = [&]() {
#pragma unroll
    for (int i = 0; i < 2; ++i)
      async_cp16(x + (size_t)(m0 + i * 32 + w * 8 + r8) * H_DIM + n0 + l7 * 8,
                 lds + XOFF + (i * 32 + w * 8) * 64);
  };

  f32x4 acc[2][2] = {};
  auto kchunk = [&](int d) {
    const u16* base = lds + d * 8192;
#pragma unroll
    for (int ks = 0; ks < 2; ++ks) {
      const int ce = ks * 32 + lrow * 8;
      bf16x8 a[2], b[2];
#pragma unroll
      for (int i = 0; i < 2; ++i) {
        int row = mq + i * 16 + lcol;
        a[i] = *(const bf16x8*)(base + row * 64 + (ce ^ ((row & 7) << 3)));
      }
#pragma unroll
      for (int j = 0; j < 2; ++j) {
        int row = nq + j * 16 + lcol;
        b[j] = *(const bf16x8*)(base + 4096 + row * 64 + (ce ^ ((row & 7) << 3)));
      }
#pragma unroll
      for (int i = 0; i < 2; ++i)
#pragma unroll
        for (int j = 0; j < 2; ++j)
          acc[i][j] = __builtin_amdgcn_mfma_f32_16x16x32_bf16(a[i], b[j], acc[i][j], 0, 0, 0);
    }
  };

  if (A != nullptr) {
    if (MODE == 1) stage_x();
    stage(0, 0); stage(1, 1); stage(2, 2);
#pragma unroll
    for (int kk = 0; kk < 16; ++kk) {
      if (kk <= 13)      asm volatile("s_waitcnt vmcnt(8)" ::: "memory");
      else if (kk == 14) asm volatile("s_waitcnt vmcnt(4)" ::: "memory");
      else               asm volatile("s_waitcnt vmcnt(0)" ::: "memory");
      __builtin_amdgcn_s_barrier();
      kchunk(kk % 3);
      __builtin_amdgcn_s_barrier();
      if (kk <= 12) stage(kk + 3, kk % 3);
    }
  } else {
    if (MODE == 1) stage_x();
    asm volatile("s_waitcnt vmcnt(0)" ::: "memory");
    __builtin_amdgcn_s_barrier();
  }

  float bv[2] = {bias[n0 + nq + lcol], bias[n0 + nq + 16 + lcol]};
  if (MODE == 2) {
#pragma unroll
    for (int i = 0; i < 2; ++i)
#pragma unroll
      for (int rr = 0; rr < 4; ++rr) {
        int row = m0 + mq + i * 16 + lrow * 4 + rr;
#pragma unroll
        for (int j = 0; j < 2; ++j)
          ((float*)outp)[(size_t)row * O_DIM + n0 + nq + j * 16 + lcol] =
              acc[i][j][rr] + bv[j];
      }
  } else {
#pragma unroll
    for (int i = 0; i < 2; ++i)
#pragma unroll
      for (int rr = 0; rr < 4; ++rr) {
        int rowl = mq + i * 16 + lrow * 4 + rr;
#pragma unroll
        for (int j = 0; j < 2; ++j) {
          int col = nq + j * 16 + lcol;
          float v = acc[i][j][rr] + bv[j] + bf2f(lds[XOFF + rowl * 64 + col]);
          lds[rowl * 64 + col] = f2bf(fast_tanh(v));
        }
      }
    __syncthreads();
    {
      int row = tid >> 2, c = (tid & 3) * 16;
      const uint4* s = (const uint4*)(lds + row * 64 + c);
      uint4 v0 = s[0], v1 = s[1];
      uint4* g = (uint4*)((u16*)outp + (size_t)(m0 + row) * H_DIM + n0 + c);
      g[0] = v0;
      g[1] = v1;
    }
  }
}

// ---------------------------------------------------------------------------
extern "C" void kernel_launch(void* const* d_in, const int* in_sizes, int n_in,
                              void* d_out, int out_size, void* d_ws, size_t ws_size,
                              hipStream_t stream) {
  const float* msg  = (const float*)d_in[0];
  const float* Wemb = (const float*)d_in[1];
  const float* bemb = (const float*)d_in[2];
  const float* Wih  = (const float*)d_in[3];
  const float* bih  = (const float*)d_in[4];
  const float* Whh  = (const float*)d_in[5];
  const float* bhh  = (const float*)d_in[6];
  const float* Wout = (const float*)d_in[7];
  const float* bout = (const float*)d_in[8];
  char* ws = (char*)d_ws;

  // ws layout (bytes)
  float* bc   = (float*)ws;               // 4 KB
  u16* Wc     = (u16*)(ws + 4096);        // 2 MB
  u16* Whh_b  = (u16*)(ws + 2101248);     // 2 MB
  u16* Wout_b = (u16*)(ws + 4198400);     // 2 MB
  u16* hA     = (u16*)(ws + 6295552);     // 2 MB (fallback path only)
  u16* hB     = (u16*)(ws + 8392704);     // 2 MB (fallback path only)
  u16* xp     = (u16*)(ws + 10489856);    // 64 MB
  u16* msgb   = (u16*)(ws + 77598720);    // 64 MB (only if ws big enough)
  // A3/B3 (3 MB each) transiently occupy the START of the xp region: fully
  // consumed by wcomb_mfma BEFORE gemm_xp/xproj overwrites xp.
  u16* A3     = (u16*)(ws + 10489856);
  u16* B3     = (u16*)(ws + 10489856 + 3145728);
  const size_t NEED_SMALL = 77598720;
  const size_t NEED_BIG   = 77598720 + 67108864;
  if (ws_size < NEED_SMALL) return;
  const bool big = ws_size >= NEED_BIG;

  prep_all<<<2308, 256, 0, stream>>>(Whh, Wout, big ? msg : nullptr, Wih, Wemb,
                                     bemb, bih, Whh_b, Wout_b,
                                     big ? msgb : nullptr, A3, B3, bc);
  wcomb_mfma<<<256, 256, 0, stream>>>(A3, B3, Wc);

  if (big) {
    // xproj + t=0 fold: h0 lands in xp slot 0
    gemm_xp<<<2048, 256, 0, stream>>>(msgb, Wc, bc, bhh, xp);
    // ONE launch: 31 recurrence steps + output GEMM (row-local chain)
    rnn_all<<<64, 512, 0, stream>>>(Whh_b, Wout_b, xp, bhh, bout, (float*)d_out);
  } else {
    xproj_mfma<<<dim3(8, 256), 256, 0, stream>>>(msg, Wc, bc, xp);
    step64<1><<<256, 256, 0, stream>>>(nullptr, Whh_b, xp, bhh, hA);
    for (int t = 1; t < 32; ++t) {
      const u16* hin = (t & 1) ? hA : hB;
      u16* hout = (t & 1) ? hB : hA;
      step64<1><<<256, 256, 0, stream>>>(hin, Whh_b,
                                         xp + (size_t)t * B_DIM * H_DIM, bhh, hout);
    }
    step64<2><<<256, 256, 0, stream>>>(hB, Wout_b, nullptr, bout, d_out);
  }
}